// Round 8
// baseline (270.684 us; speedup 1.0000x reference)
//
#include <hip/hip_runtime.h>
#include <stdint.h>

#define Bc   2
#define Lc   1024
#define Pc   1024
#define Tc   2048
#define HIDc 2048
#define NHc  32
#define NKVc 8
#define Dc   64

typedef __bf16 bf16x8 __attribute__((ext_vector_type(8)));
typedef float f32x4 __attribute__((ext_vector_type(4)));
typedef float f32x16 __attribute__((ext_vector_type(16)));

__device__ inline unsigned short f2bf(float f) {
  union { float f; uint32_t u; } v; v.f = f;
  uint32_t u = v.u;
  uint32_t r = (u + 0x7fffu + ((u >> 16) & 1u)) >> 16;
  return (unsigned short)r;
}
__device__ inline float bf2f(unsigned short h) {
  union { uint32_t u; float f; } v; v.u = ((uint32_t)h) << 16;
  return v.f;
}
__device__ inline float exp2_fast(float x) {
#if defined(__has_builtin)
#if __has_builtin(__builtin_amdgcn_exp2f)
  return __builtin_amdgcn_exp2f(x);
#else
  return exp2f(x);
#endif
#else
  return exp2f(x);
#endif
}
// pack two f32 -> one u32 of 2x bf16 (low = a, high = b); no builtin on gfx950
__device__ inline unsigned int cvtpk_bf16(float a, float b) {
  unsigned int r;
  asm("v_cvt_pk_bf16_f32 %0, %1, %2" : "=v"(r) : "v"(a), "v"(b));
  return r;
}
// v_permlane32_swap_b32: a.hi32lanes <-> b.lo32lanes
__device__ inline void plane32_swap(unsigned int& a, unsigned int& b) {
  asm("v_permlane32_swap_b32 %0, %1" : "+v"(a), "+v"(b));
}

typedef const __attribute__((address_space(1))) unsigned int* gas1_t;
typedef __attribute__((address_space(3))) unsigned int* las3_t;
__device__ inline void gload_lds16(const void* g, void* l) {
  __builtin_amdgcn_global_load_lds((gas1_t)g, (las3_t)l, 16, 0, 0);
}

// ---------------- cast x (fp32 -> bf16) ----------------
__global__ void cast_x_kernel(const float* __restrict__ x, unsigned short* __restrict__ xb) {
  int i = (blockIdx.x * 256 + threadIdx.x) * 4;
  float4 v = *(const float4*)(x + i);
  ushort4 o;
  o.x = f2bf(v.x); o.y = f2bf(v.y); o.z = f2bf(v.z); o.w = f2bf(v.w);
  *(ushort4*)(xb + i) = o;
}

// ---- fused transpose+cast of all 4 weights ----
__global__ void transpose_all_kernel(const float* __restrict__ Wq, const float* __restrict__ Wk,
                                     const float* __restrict__ Wv, const float* __restrict__ Wo,
                                     unsigned short* __restrict__ WqkvT,
                                     unsigned short* __restrict__ WoT) {
  __shared__ float s[32][33];
  int bx = blockIdx.x, k0 = blockIdx.y * 32;
  const float* W;
  unsigned short* dst;
  int N, n0, drow;
  if (bx < 64)       { W = Wq; dst = WqkvT; N = 2048; n0 = bx * 32;        drow = n0; }
  else if (bx < 80)  { W = Wk; dst = WqkvT; N = 512;  n0 = (bx - 64) * 32; drow = 2048 + n0; }
  else if (bx < 96)  { W = Wv; dst = WqkvT; N = 512;  n0 = (bx - 80) * 32; drow = 2560 + n0; }
  else               { W = Wo; dst = WoT;   N = 2048; n0 = (bx - 96) * 32; drow = n0; }
  int tx = threadIdx.x, ty = threadIdx.y;  // (32,8)
#pragma unroll
  for (int j = 0; j < 4; ++j)
    s[ty + j * 8][tx] = W[(size_t)(k0 + ty + j * 8) * N + n0 + tx];
  __syncthreads();
#pragma unroll
  for (int j = 0; j < 4; ++j)
    dst[(size_t)(drow + ty + j * 8) * 2048 + k0 + tx] = f2bf(s[tx][ty + j * 8]);
}

// ---------------- GEMM: TM x 128 tile, pipelined K-loop ----------------
// R7 fix: launch_bounds was (256,2) = 2 blocks/CU cap. The guide's m97-
// structure reference numbers (874-912 TF) run at ~3 blocks/CU (m114) --
// implicit wave overlap across blocks hides the per-K-step barrier drain.
// TM=128: 32KB LDS -> 3 blocks/CU (96KB), VGPR ~120 < 170-cap at 12 waves/CU.
// TM=64: 24KB LDS -> 4 blocks/CU, VGPR ~90 < 128-cap.
template <int TM, bool OUT_F32>
__global__ __launch_bounds__(256, TM == 128 ? 3 : 4) void gemm_kernel(
    const unsigned short* __restrict__ A, const unsigned short* __restrict__ BT,
    const float* __restrict__ bq, const float* __restrict__ bk, const float* __restrict__ bv,
    void* __restrict__ Cout, int N) {
  const int K = 2048;
  const int MI = TM / 32;       // m-frags per wave
  __shared__ unsigned short sA[2][TM * 32];
  __shared__ unsigned short sB[2][128 * 32];
  const int m0 = blockIdx.y * TM, n0 = blockIdx.x * 128;
  const int tid = threadIdx.x;
  const int lane = tid & 63, w = tid >> 6;
  const int l15 = lane & 15, quad = lane >> 4;
  const int wm = (w & 1) * (TM / 2), wn = (w >> 1) * 64;

  f32x4 acc[MI][4];
#pragma unroll
  for (int i = 0; i < MI; ++i)
#pragma unroll
    for (int j = 0; j < 4; ++j) {
      f32x4 z = {0.f, 0.f, 0.f, 0.f};
      acc[i][j] = z;
    }

  const unsigned short* ga = A + (size_t)(m0 + (tid >> 2)) * K + (tid & 3) * 8;
  const unsigned short* gb = BT + (size_t)(n0 + (tid >> 2)) * K + (tid & 3) * 8;

  auto issue = [&](int tile, int buf) {
    int kb = tile * 32;
#pragma unroll
    for (int i = 0; i < TM / 64; ++i)
      gload_lds16(ga + (size_t)(i * 64) * K + kb, &sA[buf][i * 64 * 32 + tid * 8]);
    gload_lds16(gb + kb, &sB[buf][tid * 8]);
    gload_lds16(gb + (size_t)64 * K + kb, &sB[buf][64 * 32 + tid * 8]);
  };

  issue(0, 0);
  for (int t = 0; t < 64; ++t) {
    int tn = (t + 1 < 64) ? t + 1 : 63;  // clamped dummy prefetch on last iter
    issue(tn, (t + 1) & 1);
    if (TM == 128)
      asm volatile("s_waitcnt vmcnt(4)" ::: "memory");
    else
      asm volatile("s_waitcnt vmcnt(3)" ::: "memory");
    __builtin_amdgcn_s_barrier();
    const unsigned short* bA = sA[t & 1];
    const unsigned short* bB = sB[t & 1];
    bf16x8 af[MI], bfr[4];
#pragma unroll
    for (int i = 0; i < MI; ++i)
      af[i] = *(const bf16x8*)(bA + (wm + i * 16 + l15) * 32 + quad * 8);
#pragma unroll
    for (int i = 0; i < 4; ++i)
      bfr[i] = *(const bf16x8*)(bB + (wn + i * 16 + l15) * 32 + quad * 8);
#pragma unroll
    for (int mi = 0; mi < MI; ++mi)
#pragma unroll
      for (int ni = 0; ni < 4; ++ni)
        acc[mi][ni] = __builtin_amdgcn_mfma_f32_16x16x32_bf16(af[mi], bfr[ni], acc[mi][ni], 0, 0, 0);
    asm volatile("s_waitcnt lgkmcnt(0)" ::: "memory");
    __builtin_amdgcn_s_barrier();
  }

#pragma unroll
  for (int mi = 0; mi < MI; ++mi)
#pragma unroll
    for (int ni = 0; ni < 4; ++ni) {
      int col = n0 + wn + ni * 16 + l15;
      float bvv = 0.f;
      if (bq) bvv = (col < 2048) ? bq[col] : (col < 2560 ? bk[col - 2048] : bv[col - 2560]);
#pragma unroll
      for (int r = 0; r < 4; ++r) {
        int row = m0 + wm + mi * 16 + quad * 4 + r;
        float v = acc[mi][ni][r] + bvv;
        if (OUT_F32)
          ((float*)Cout)[(size_t)row * N + col] = v;
        else
          ((unsigned short*)Cout)[(size_t)row * N + col] = f2bf(v);
      }
    }
}

// ------- fused KV-cache build, FRAGMENT-LINEAR output layout -------
// Kc/Vc layout: [bh][tile(32)][frag(8)][lane(64)][8 bf16]  (4 MB each).
// K frag f=mf*4+ks, lane l: K[t0+mf*32+(l&31)][ks*16+(l>>5)*8+j]
// V frag f=md*4+ks, lane l: V^T[md*32+(l&31)][t0+ks*16+(l>>5)*8+j]
__global__ void build_kv_kernel(const unsigned short* __restrict__ qkv,
                                const float* __restrict__ past_k,
                                const float* __restrict__ past_v,
                                const float* __restrict__ cosb, const float* __restrict__ sinb,
                                unsigned short* __restrict__ Kc,
                                unsigned short* __restrict__ Vc) {
  __shared__ __align__(16) unsigned short sK[64 * 72];   // [t-local][d], stride 72
  __shared__ __align__(16) unsigned short sVT[64 * 72];  // [d][t-local], stride 72
  union U8 { bf16x8 v; unsigned short u[8]; };

  const int bid = blockIdx.x;         // bh*32 + tt
  const int bh = bid >> 5, tt = bid & 31;
  const int b = bh >> 3, hk = bh & 7;
  const int tid = threadIdx.x;
  const int tl = tid >> 2;            // 0..63 row in tile
  const int c16 = (tid & 3) * 16;     // col start

  const int t = tt * 64 + tl;

  // ---- K row -> sK[t][d] ----
  U8 ko0, ko1;
  if (tt < 16) {
    const float* src = past_k + (((size_t)bh * 1024 + t) * 64 + c16);
#pragma unroll
    for (int i = 0; i < 8; ++i) ko0.u[i] = f2bf(src[i]);
#pragma unroll
    for (int i = 0; i < 8; ++i) ko1.u[i] = f2bf(src[8 + i]);
  } else {
    const int l = t - 1024;
    const unsigned short* krow = qkv + ((size_t)(b * 1024 + l)) * 3072 + 2048 + hk * 64;
    const int po = (c16 < 32) ? 32 : -32;
    const float sgn = (c16 < 32) ? -1.f : 1.f;
    U8 own0, own1, par0, par1;
    own0.v = *(const bf16x8*)(krow + c16);
    own1.v = *(const bf16x8*)(krow + c16 + 8);
    par0.v = *(const bf16x8*)(krow + c16 + po);
    par1.v = *(const bf16x8*)(krow + c16 + po + 8);
    const float* cb = cosb + l * 64 + c16;
    const float* sb = sinb + l * 64 + c16;
#pragma unroll
    for (int i = 0; i < 8; ++i)
      ko0.u[i] = f2bf(bf2f(own0.u[i]) * cb[i] + sgn * bf2f(par0.u[i]) * sb[i]);
#pragma unroll
    for (int i = 0; i < 8; ++i)
      ko1.u[i] = f2bf(bf2f(own1.u[i]) * cb[8 + i] + sgn * bf2f(par1.u[i]) * sb[8 + i]);
  }
  *(bf16x8*)&sK[tl * 72 + c16] = ko0.v;
  *(bf16x8*)&sK[tl * 72 + c16 + 8] = ko1.v;

  // ---- V row -> sVT[d][t] (transpose via scalar writes) ----
  if (tt < 16) {
    const float* src = past_v + (((size_t)bh * 1024 + t) * 64 + c16);
#pragma unroll
    for (int i = 0; i < 16; ++i) sVT[(c16 + i) * 72 + tl] = f2bf(src[i]);
  } else {
    const unsigned short* vrow = qkv + ((size_t)(b * 1024 + (t - 1024))) * 3072 + 2560 + hk * 64 + c16;
    U8 v0, v1;
    v0.v = *(const bf16x8*)(vrow);
    v1.v = *(const bf16x8*)(vrow + 8);
#pragma unroll
    for (int i = 0; i < 8; ++i) sVT[(c16 + i) * 72 + tl] = v0.u[i];
#pragma unroll
    for (int i = 0; i < 8; ++i) sVT[(c16 + 8 + i) * 72 + tl] = v1.u[i];
  }

  __syncthreads();

  // ---- write frag-linear chunks (coalesced 16B global stores) ----
  unsigned short* KD = Kc + (size_t)bh * 131072 + (size_t)tt * 4096;
  unsigned short* VD = Vc + (size_t)bh * 131072 + (size_t)tt * 4096;
#pragma unroll
  for (int half = 0; half < 2; ++half) {
    int c = tid + half * 256;
    int f = c >> 6, l = c & 63;
    int col = (f & 3) * 16 + (l >> 5) * 8;
    int row = (f >> 2) * 32 + (l & 31);
    *(bf16x8*)(KD + f * 512 + l * 8) = *(const bf16x8*)&sK[row * 72 + col];
    *(bf16x8*)(VD + f * 512 + l * 8) = *(const bf16x8*)&sVT[row * 72 + col];
  }
}

// ---------------- flash attention v11 (FROZEN from R7 win): V via global_load_lds ----------------
// attn counters R7: 51.9us, VGPR 64, WRITE_SIZE 8192 (no spill), MfmaUtil 20%,
// VALUBusy 38%, occ 32%. Kept identical this round for clean GEMM attribution.
__global__ __launch_bounds__(256, 4) void attn_kernel(
    const unsigned short* __restrict__ qkv,  // [B*L][3072]
    const unsigned short* __restrict__ Kc,   // frag-linear
    const unsigned short* __restrict__ Vc,   // frag-linear
    const float* __restrict__ cosb, const float* __restrict__ sinb,
    unsigned short* __restrict__ O) {        // [B*L][2048]
  // union: main loop uses vstage[4][4096] (32 KB); epilogue uses
  // comb[4][32][68] f32 (34816 B) + lsmem[4][32] (512 B) = 35328 B
  __shared__ __align__(16) char smraw[35328];
  unsigned short* vst = (unsigned short*)smraw;             // [4][4096]
  float (*comb)[32][68] = (float (*)[32][68])smraw;
  float* lsmem = (float*)(smraw + 34816);                   // [4][32]

  const int flat = blockIdx.x;               // 0..2047
  const int hk = flat & 7;                   // XCD-pinned (2048%8==0)
  const int b = (flat >> 3) & 1;
  const int h2 = (flat >> 4) & 3;
  const int qt = flat >> 6;                  // 0..31
  const int h = hk * 4 + h2;
  const int q0 = qt * 32;
  const int bh = b * 8 + hk;

  const int tid = threadIdx.x;
  const int lane = tid & 63, w = tid >> 6;
  const int l31 = lane & 31, hh = lane >> 5;

  union U8 { bf16x8 v; unsigned short u[8]; };
  union PB { unsigned int w4[4]; bf16x8 v; };

  const unsigned short* KT = Kc + (size_t)bh * 131072;
  const unsigned short* VT = Vc + (size_t)bh * 131072;
  unsigned short* vwave = vst + w * 4096;    // wave-private V stage (8 KB)

  // Q as persistent B-operand frags: lane holds Q[d][q=l31], frag ks covers
  // d = ks*16 + hh*8 + j; RoPE + scale*log2(e) folded in.
  const float SC = 0.125f * 1.44269504f;
  bf16x8 qB[4];
  {
    int row = q0 + l31;
    const unsigned short* qrow = qkv + (size_t)(b * 1024 + row) * 3072 + h * 64;
    U8 raw[4];
#pragma unroll
    for (int ks = 0; ks < 4; ++ks)
      raw[ks].v = *(const bf16x8*)(qrow + ks * 16 + hh * 8);
#pragma unroll
    for (int ks = 0; ks < 2; ++ks) {
      int dbase = ks * 16 + hh * 8;
      float4 ca = *(const float4*)(cosb + row * 64 + dbase);
      float4 cb = *(const float4*)(cosb + row * 64 + dbase + 4);
      float4 sa = *(const float4*)(sinb + row * 64 + dbase);
      float4 sb = *(const float4*)(sinb + row * 64 + dbase + 4);
      float c[8] = {ca.x, ca.y, ca.z, ca.w, cb.x, cb.y, cb.z, cb.w};
      float sn[8] = {sa.x, sa.y, sa.z, sa.w, sb.x, sb.y, sb.z, sb.w};
      U8 flo, fhi;
#pragma unroll
      for (int j = 0; j < 8; ++j) {
        float ql = bf2f(raw[ks].u[j]), qh = bf2f(raw[ks + 2].u[j]);
        float cc = c[j] * SC, ss = sn[j] * SC;
        flo.u[j] = f2bf(ql * cc - qh * ss);
        fhi.u[j] = f2bf(qh * cc + ql * ss);
      }
      qB[ks] = flo.v;
      qB[ks + 2] = fhi.v;
    }
  }

  f32x16 oaccT[2];
  {
    f32x16 z;
#pragma unroll
    for (int i = 0; i < 16; ++i) z[i] = 0.f;
    oaccT[0] = z; oaccT[1] = z;
  }
  float lsum = 0.f;

  const int ntile = (q0 + 1119) >> 6;        // 17..32

  for (int kt = w; kt < ntile; kt += 4) {
    // compiler fence: keep this iteration's DMA after last iteration's V reads
    asm volatile("" ::: "memory");
    // async V stage (no registers): frag f -> vwave[f*512 + lane*8]
    const unsigned short* vb = VT + (size_t)kt * 4096 + lane * 8;
#pragma unroll
    for (int f = 0; f < 8; ++f)
      gload_lds16(vb + f * 512, vwave + f * 512);

    // K frags direct to registers (the one exposed latency per tile)
    const unsigned short* kb = KT + (size_t)kt * 4096 + lane * 8;
    bf16x8 kf[8];
#pragma unroll
    for (int f = 0; f < 8; ++f) kf[f] = *(const bf16x8*)(kb + f * 512);

    // S^T = K @ (Q*SC')
    f32x16 sacc[2];
    {
      f32x16 z;
#pragma unroll
      for (int i = 0; i < 16; ++i) z[i] = 0.f;
      sacc[0] = z; sacc[1] = z;
    }
#pragma unroll
    for (int ks = 0; ks < 4; ++ks)
      sacc[0] = __builtin_amdgcn_mfma_f32_32x32x16_bf16(kf[ks], qB[ks], sacc[0], 0, 0, 0);
#pragma unroll
    for (int ks = 0; ks < 4; ++ks)
      sacc[1] = __builtin_amdgcn_mfma_f32_32x32x16_bf16(kf[4 + ks], qB[ks], sacc[1], 0, 0, 0);

    // in-register softmax-lite: lane owns q=q0+l31; t = t0+mf*32+(r&3)+8*(r>>2)+4*hh
    const int t0 = kt * 64;
    unsigned int pk[2][8];
    const bool diag = (t0 + 63 > q0 + Pc);
    if (!diag) {
#pragma unroll
      for (int mf = 0; mf < 2; ++mf)
#pragma unroll
        for (int p = 0; p < 8; ++p) {
          float e0 = exp2_fast(sacc[mf][2 * p]);
          float e1 = exp2_fast(sacc[mf][2 * p + 1]);
          lsum += e0 + e1;
          pk[mf][p] = cvtpk_bf16(e0, e1);
        }
    } else {
      int rg = q0 + l31 + Pc;
#pragma unroll
      for (int mf = 0; mf < 2; ++mf)
#pragma unroll
        for (int p = 0; p < 8; ++p) {
          int r0 = 2 * p;
          int tg = t0 + mf * 32 + (r0 & 3) + 8 * (r0 >> 2) + 4 * hh;
          float e0 = (tg <= rg) ? exp2_fast(sacc[mf][r0]) : 0.f;
          float e1 = (tg + 1 <= rg) ? exp2_fast(sacc[mf][r0 + 1]) : 0.f;
          lsum += e0 + e1;
          pk[mf][p] = cvtpk_bf16(e0, e1);
        }
    }

    // P^T -> PV B-frags (verified v7 mapping)
    PB pb[4];
#pragma unroll
    for (int ks = 0; ks < 4; ++ks) {
      int mf = ks >> 1, o = (ks & 1) * 4;
      unsigned int a0 = pk[mf][o + 0], b0 = pk[mf][o + 2];
      unsigned int a1 = pk[mf][o + 1], b1 = pk[mf][o + 3];
      plane32_swap(a0, b0);
      plane32_swap(a1, b1);
      pb[ks].w4[0] = a0; pb[ks].w4[1] = a1; pb[ks].w4[2] = b0; pb[ks].w4[3] = b1;
    }

    // V DMA has been in flight since tile top; drain and read frags from LDS
    asm volatile("s_waitcnt vmcnt(0)" ::: "memory");
    bf16x8 vf[8];
#pragma unroll
    for (int f = 0; f < 8; ++f)
      vf[f] = *(const bf16x8*)(vwave + f * 512 + lane * 8);

    // O^T += V^T @ P^T
#pragma unroll
    for (int md = 0; md < 2; ++md)
#pragma unroll
      for (int ks = 0; ks < 4; ++ks)
        oaccT[md] = __builtin_amdgcn_mfma_f32_32x32x16_bf16(vf[md * 4 + ks], pb[ks].v, oaccT[md], 0, 0, 0);
  }

  // ---- additive 4-wave combine (comb aliases vstage: barrier first) ----
  __syncthreads();
  lsum += __shfl_xor(lsum, 32);
  if (hh == 0) lsmem[w * 32 + l31] = lsum;
#pragma unroll
  for (int md = 0; md < 2; ++md)
#pragma unroll
    for (int g = 0; g < 4; ++g) {
      float4 fv = {oaccT[md][4 * g + 0], oaccT[md][4 * g + 1],
                   oaccT[md][4 * g + 2], oaccT[md][4 * g + 3]};
      *(float4*)&comb[w][l31][md * 32 + 8 * g + 4 * hh] = fv;
    }
  __syncthreads();

  const int q = tid >> 3, c8 = (tid & 7) * 8;
  float a8[8];
#pragma unroll
  for (int i = 0; i < 8; ++i) a8[i] = 0.f;
#pragma unroll
  for (int wv = 0; wv < 4; ++wv) {
    float4 p0 = *(const float4*)&comb[wv][q][c8];
    float4 p1 = *(const float4*)&comb[wv][q][c8 + 4];
    a8[0] += p0.x; a8[1] += p0.y; a8[2] += p0.z; a8[3] += p0.w;
    a8[4] += p1.x; a8[5] += p1.y; a8[6] += p1.z; a8[7] += p1.w;
  }
  float linv = 1.f / (lsmem[0 * 32 + q] + lsmem[1 * 32 + q] + lsmem[2 * 32 + q] + lsmem[3 * 32 + q]);
  uint4 ov;
  ov.x = cvtpk_bf16(a8[0] * linv, a8[1] * linv);
  ov.y = cvtpk_bf16(a8[2] * linv, a8[3] * linv);
  ov.z = cvtpk_bf16(a8[4] * linv, a8[5] * linv);
  ov.w = cvtpk_bf16(a8[6] * linv, a8[7] * linv);
  int row = b * 1024 + q0 + q;
  *(uint4*)(O + (size_t)row * 2048 + h * 64 + c8) = ov;
}

extern "C" void kernel_launch(void* const* d_in, const int* in_sizes, int n_in,
                              void* d_out, int out_size, void* d_ws, size_t ws_size,
                              hipStream_t stream) {
  const float* x      = (const float*)d_in[0];
  const float* cosb   = (const float*)d_in[2];
  const float* sinb   = (const float*)d_in[3];
  const float* past_k = (const float*)d_in[4];
  const float* past_v = (const float*)d_in[5];
  const float* Wq     = (const float*)d_in[6];
  const float* bq     = (const float*)d_in[7];
  const float* Wk     = (const float*)d_in[8];
  const float* bk     = (const float*)d_in[9];
  const float* Wv     = (const float*)d_in[10];
  const float* bv     = (const float*)d_in[11];
  const float* Wo     = (const float*)d_in[12];
  float* out = (float*)d_out;

  char* ws = (char*)d_ws;
  unsigned short* xb    = (unsigned short*)(ws + ((size_t)0 << 20));   // 8 MB
  unsigned short* WqkvT = (unsigned short*)(ws + ((size_t)8 << 20));   // 12 MB
  unsigned short* WoT   = (unsigned short*)(ws + ((size_t)20 << 20));  // 8 MB
  unsigned short* qkvb  = (unsigned short*)(ws + ((size_t)28 << 20));  // 12 MB
  unsigned short* Kc    = (unsigned short*)(ws + ((size_t)40 << 20));  // 4 MB
  unsigned short* Vc    = (unsigned short*)(ws + ((size_t)44 << 20));  // 4 MB
  unsigned short* attno = (unsigned short*)(ws + ((size_t)48 << 20));  // 8 MB

  cast_x_kernel<<<4096, 256, 0, stream>>>(x, xb);
  transpose_all_kernel<<<dim3(160, 64), dim3(32, 8), 0, stream>>>(Wq, Wk, Wv, Wo, WqkvT, WoT);

  // QKV projection: 128^2 tile at 3 blocks/CU (the m97-structure operating point)
  gemm_kernel<128, false><<<dim3(24, 16), 256, 0, stream>>>(xb, WqkvT, bq, bk, bv, qkvb, 3072);

  build_kv_kernel<<<512, 256, 0, stream>>>(qkvb, past_k, past_v, cosb, sinb, Kc, Vc);

  attn_kernel<<<2048, 256, 0, stream>>>(qkvb, Kc, Vc, cosb, sinb, attno);

  // Wo projection: 128^2 tile, 16x16 = 256 blocks
  gemm_kernel<128, true><<<dim3(16, 16), 256, 0, stream>>>(attno, WoT, nullptr, nullptr, nullptr, out, 2048);
}

// Round 9
// 265.092 us; speedup vs baseline: 1.0211x; 1.0211x over previous
//
#include <hip/hip_runtime.h>
#include <stdint.h>

#define Bc   2
#define Lc   1024
#define Pc   1024
#define Tc   2048
#define HIDc 2048
#define NHc  32
#define NKVc 8
#define Dc   64

typedef __bf16 bf16x8 __attribute__((ext_vector_type(8)));
typedef float f32x4 __attribute__((ext_vector_type(4)));
typedef float f32x16 __attribute__((ext_vector_type(16)));

__device__ inline unsigned short f2bf(float f) {
  union { float f; uint32_t u; } v; v.f = f;
  uint32_t u = v.u;
  uint32_t r = (u + 0x7fffu + ((u >> 16) & 1u)) >> 16;
  return (unsigned short)r;
}
__device__ inline float bf2f(unsigned short h) {
  union { uint32_t u; float f; } v; v.u = ((uint32_t)h) << 16;
  return v.f;
}
__device__ inline float exp2_fast(float x) {
#if defined(__has_builtin)
#if __has_builtin(__builtin_amdgcn_exp2f)
  return __builtin_amdgcn_exp2f(x);
#else
  return exp2f(x);
#endif
#else
  return exp2f(x);
#endif
}
// pack two f32 -> one u32 of 2x bf16 (low = a, high = b); no builtin on gfx950
__device__ inline unsigned int cvtpk_bf16(float a, float b) {
  unsigned int r;
  asm("v_cvt_pk_bf16_f32 %0, %1, %2" : "=v"(r) : "v"(a), "v"(b));
  return r;
}
// v_permlane32_swap_b32: a.hi32lanes <-> b.lo32lanes
__device__ inline void plane32_swap(unsigned int& a, unsigned int& b) {
  asm("v_permlane32_swap_b32 %0, %1" : "+v"(a), "+v"(b));
}

typedef const __attribute__((address_space(1))) unsigned int* gas1_t;
typedef __attribute__((address_space(3))) unsigned int* las3_t;
__device__ inline void gload_lds16(const void* g, void* l) {
  __builtin_amdgcn_global_load_lds((gas1_t)g, (las3_t)l, 16, 0, 0);
}

// ---------------- cast x (fp32 -> bf16) ----------------
__global__ void cast_x_kernel(const float* __restrict__ x, unsigned short* __restrict__ xb) {
  int i = (blockIdx.x * 256 + threadIdx.x) * 4;
  float4 v = *(const float4*)(x + i);
  ushort4 o;
  o.x = f2bf(v.x); o.y = f2bf(v.y); o.z = f2bf(v.z); o.w = f2bf(v.w);
  *(ushort4*)(xb + i) = o;
}

// ---- fused transpose+cast of all 4 weights ----
__global__ void transpose_all_kernel(const float* __restrict__ Wq, const float* __restrict__ Wk,
                                     const float* __restrict__ Wv, const float* __restrict__ Wo,
                                     unsigned short* __restrict__ WqkvT,
                                     unsigned short* __restrict__ WoT) {
  __shared__ float s[32][33];
  int bx = blockIdx.x, k0 = blockIdx.y * 32;
  const float* W;
  unsigned short* dst;
  int N, n0, drow;
  if (bx < 64)       { W = Wq; dst = WqkvT; N = 2048; n0 = bx * 32;        drow = n0; }
  else if (bx < 80)  { W = Wk; dst = WqkvT; N = 512;  n0 = (bx - 64) * 32; drow = 2048 + n0; }
  else if (bx < 96)  { W = Wv; dst = WqkvT; N = 512;  n0 = (bx - 80) * 32; drow = 2560 + n0; }
  else               { W = Wo; dst = WoT;   N = 2048; n0 = (bx - 96) * 32; drow = n0; }
  int tx = threadIdx.x, ty = threadIdx.y;  // (32,8)
#pragma unroll
  for (int j = 0; j < 4; ++j)
    s[ty + j * 8][tx] = W[(size_t)(k0 + ty + j * 8) * N + n0 + tx];
  __syncthreads();
#pragma unroll
  for (int j = 0; j < 4; ++j)
    dst[(size_t)(drow + ty + j * 8) * 2048 + k0 + tx] = f2bf(s[tx][ty + j * 8]);
}

// ---------------- GEMM: TM x 128 tile, pipelined K-loop ----------------
// TM=64 @ launch_bounds(256,4): 24KB LDS -> up to 6 blocks/CU, VGPR ~90 < 128
// cap; cross-block wave overlap (m114) hides the per-K-step barrier drain.
template <int TM, bool OUT_F32>
__global__ __launch_bounds__(256, TM == 128 ? 3 : 4) void gemm_kernel(
    const unsigned short* __restrict__ A, const unsigned short* __restrict__ BT,
    const float* __restrict__ bq, const float* __restrict__ bk, const float* __restrict__ bv,
    void* __restrict__ Cout, int N) {
  const int K = 2048;
  const int MI = TM / 32;       // m-frags per wave
  __shared__ unsigned short sA[2][TM * 32];
  __shared__ unsigned short sB[2][128 * 32];
  const int m0 = blockIdx.y * TM, n0 = blockIdx.x * 128;
  const int tid = threadIdx.x;
  const int lane = tid & 63, w = tid >> 6;
  const int l15 = lane & 15, quad = lane >> 4;
  const int wm = (w & 1) * (TM / 2), wn = (w >> 1) * 64;

  f32x4 acc[MI][4];
#pragma unroll
  for (int i = 0; i < MI; ++i)
#pragma unroll
    for (int j = 0; j < 4; ++j) {
      f32x4 z = {0.f, 0.f, 0.f, 0.f};
      acc[i][j] = z;
    }

  const unsigned short* ga = A + (size_t)(m0 + (tid >> 2)) * K + (tid & 3) * 8;
  const unsigned short* gb = BT + (size_t)(n0 + (tid >> 2)) * K + (tid & 3) * 8;

  auto issue = [&](int tile, int buf) {
    int kb = tile * 32;
#pragma unroll
    for (int i = 0; i < TM / 64; ++i)
      gload_lds16(ga + (size_t)(i * 64) * K + kb, &sA[buf][i * 64 * 32 + tid * 8]);
    gload_lds16(gb + kb, &sB[buf][tid * 8]);
    gload_lds16(gb + (size_t)64 * K + kb, &sB[buf][64 * 32 + tid * 8]);
  };

  issue(0, 0);
  for (int t = 0; t < 64; ++t) {
    int tn = (t + 1 < 64) ? t + 1 : 63;  // clamped dummy prefetch on last iter
    issue(tn, (t + 1) & 1);
    if (TM == 128)
      asm volatile("s_waitcnt vmcnt(4)" ::: "memory");
    else
      asm volatile("s_waitcnt vmcnt(3)" ::: "memory");
    __builtin_amdgcn_s_barrier();
    const unsigned short* bA = sA[t & 1];
    const unsigned short* bB = sB[t & 1];
    bf16x8 af[MI], bfr[4];
#pragma unroll
    for (int i = 0; i < MI; ++i)
      af[i] = *(const bf16x8*)(bA + (wm + i * 16 + l15) * 32 + quad * 8);
#pragma unroll
    for (int i = 0; i < 4; ++i)
      bfr[i] = *(const bf16x8*)(bB + (wn + i * 16 + l15) * 32 + quad * 8);
#pragma unroll
    for (int mi = 0; mi < MI; ++mi)
#pragma unroll
      for (int ni = 0; ni < 4; ++ni)
        acc[mi][ni] = __builtin_amdgcn_mfma_f32_16x16x32_bf16(af[mi], bfr[ni], acc[mi][ni], 0, 0, 0);
    asm volatile("s_waitcnt lgkmcnt(0)" ::: "memory");
    __builtin_amdgcn_s_barrier();
  }

#pragma unroll
  for (int mi = 0; mi < MI; ++mi)
#pragma unroll
    for (int ni = 0; ni < 4; ++ni) {
      int col = n0 + wn + ni * 16 + l15;
      float bvv = 0.f;
      if (bq) bvv = (col < 2048) ? bq[col] : (col < 2560 ? bk[col - 2048] : bv[col - 2560]);
#pragma unroll
      for (int r = 0; r < 4; ++r) {
        int row = m0 + wm + mi * 16 + quad * 4 + r;
        float v = acc[mi][ni][r] + bvv;
        if (OUT_F32)
          ((float*)Cout)[(size_t)row * N + col] = v;
        else
          ((unsigned short*)Cout)[(size_t)row * N + col] = f2bf(v);
      }
    }
}

// ------- fused KV-cache build, FRAGMENT-LINEAR output layout -------
// Kc/Vc layout: [bh][tile(32)][frag(8)][lane(64)][8 bf16]  (4 MB each).
// K frag f=mf*4+ks, lane l: K[t0+mf*32+(l&31)][ks*16+(l>>5)*8+j]
// V frag f=md*4+ks, lane l: V^T[md*32+(l&31)][t0+ks*16+(l>>5)*8+j]
__global__ void build_kv_kernel(const unsigned short* __restrict__ qkv,
                                const float* __restrict__ past_k,
                                const float* __restrict__ past_v,
                                const float* __restrict__ cosb, const float* __restrict__ sinb,
                                unsigned short* __restrict__ Kc,
                                unsigned short* __restrict__ Vc) {
  __shared__ __align__(16) unsigned short sK[64 * 72];   // [t-local][d], stride 72
  __shared__ __align__(16) unsigned short sVT[64 * 72];  // [d][t-local], stride 72
  union U8 { bf16x8 v; unsigned short u[8]; };

  const int bid = blockIdx.x;         // bh*32 + tt
  const int bh = bid >> 5, tt = bid & 31;
  const int b = bh >> 3, hk = bh & 7;
  const int tid = threadIdx.x;
  const int tl = tid >> 2;            // 0..63 row in tile
  const int c16 = (tid & 3) * 16;     // col start

  const int t = tt * 64 + tl;

  // ---- K row -> sK[t][d] ----
  U8 ko0, ko1;
  if (tt < 16) {
    const float* src = past_k + (((size_t)bh * 1024 + t) * 64 + c16);
#pragma unroll
    for (int i = 0; i < 8; ++i) ko0.u[i] = f2bf(src[i]);
#pragma unroll
    for (int i = 0; i < 8; ++i) ko1.u[i] = f2bf(src[8 + i]);
  } else {
    const int l = t - 1024;
    const unsigned short* krow = qkv + ((size_t)(b * 1024 + l)) * 3072 + 2048 + hk * 64;
    const int po = (c16 < 32) ? 32 : -32;
    const float sgn = (c16 < 32) ? -1.f : 1.f;
    U8 own0, own1, par0, par1;
    own0.v = *(const bf16x8*)(krow + c16);
    own1.v = *(const bf16x8*)(krow + c16 + 8);
    par0.v = *(const bf16x8*)(krow + c16 + po);
    par1.v = *(const bf16x8*)(krow + c16 + po + 8);
    const float* cb = cosb + l * 64 + c16;
    const float* sb = sinb + l * 64 + c16;
#pragma unroll
    for (int i = 0; i < 8; ++i)
      ko0.u[i] = f2bf(bf2f(own0.u[i]) * cb[i] + sgn * bf2f(par0.u[i]) * sb[i]);
#pragma unroll
    for (int i = 0; i < 8; ++i)
      ko1.u[i] = f2bf(bf2f(own1.u[i]) * cb[8 + i] + sgn * bf2f(par1.u[i]) * sb[8 + i]);
  }
  *(bf16x8*)&sK[tl * 72 + c16] = ko0.v;
  *(bf16x8*)&sK[tl * 72 + c16 + 8] = ko1.v;

  // ---- V row -> sVT[d][t] (transpose via scalar writes) ----
  if (tt < 16) {
    const float* src = past_v + (((size_t)bh * 1024 + t) * 64 + c16);
#pragma unroll
    for (int i = 0; i < 16; ++i) sVT[(c16 + i) * 72 + tl] = f2bf(src[i]);
  } else {
    const unsigned short* vrow = qkv + ((size_t)(b * 1024 + (t - 1024))) * 3072 + 2560 + hk * 64 + c16;
    U8 v0, v1;
    v0.v = *(const bf16x8*)(vrow);
    v1.v = *(const bf16x8*)(vrow + 8);
#pragma unroll
    for (int i = 0; i < 8; ++i) sVT[(c16 + i) * 72 + tl] = v0.u[i];
#pragma unroll
    for (int i = 0; i < 8; ++i) sVT[(c16 + 8 + i) * 72 + tl] = v1.u[i];
  }

  __syncthreads();

  // ---- write frag-linear chunks (coalesced 16B global stores) ----
  unsigned short* KD = Kc + (size_t)bh * 131072 + (size_t)tt * 4096;
  unsigned short* VD = Vc + (size_t)bh * 131072 + (size_t)tt * 4096;
#pragma unroll
  for (int half = 0; half < 2; ++half) {
    int c = tid + half * 256;
    int f = c >> 6, l = c & 63;
    int col = (f & 3) * 16 + (l >> 5) * 8;
    int row = (f >> 2) * 32 + (l & 31);
    *(bf16x8*)(KD + f * 512 + l * 8) = *(const bf16x8*)&sK[row * 72 + col];
    *(bf16x8*)(VD + f * 512 + l * 8) = *(const bf16x8*)&sVT[row * 72 + col];
  }
}

// ---------------- flash attention v12: v11 + issue-chain micro-cuts ----------------
// v11 (R7): 51.9us, VGPR 64, no spill, MfmaUtil 20%, VALUBusy 38%. Still
// issue/latency-bound. v12 cuts the per-tile chain without adding live state:
// (1) persistent ZERO f32x16 as the C operand of each group's first MFMA --
// kills the 32 v_mov sacc re-zeroing per tile (+16 VGPR, 64->~80 < 128 cap);
// (2) s_setprio(1) around both MFMA clusters (guide T5: +4-7% on barrier-free
// independent-wave attn, m191 -- exactly this structure); (3) K register
// loads issued BEFORE the V-DMA so QK unblocks ~8 issue slots earlier.
__global__ __launch_bounds__(256, 4) void attn_kernel(
    const unsigned short* __restrict__ qkv,  // [B*L][3072]
    const unsigned short* __restrict__ Kc,   // frag-linear
    const unsigned short* __restrict__ Vc,   // frag-linear
    const float* __restrict__ cosb, const float* __restrict__ sinb,
    unsigned short* __restrict__ O) {        // [B*L][2048]
  // union: main loop uses vstage[4][4096] (32 KB); epilogue uses
  // comb[4][32][68] f32 (34816 B) + lsmem[4][32] (512 B) = 35328 B
  __shared__ __align__(16) char smraw[35328];
  unsigned short* vst = (unsigned short*)smraw;             // [4][4096]
  float (*comb)[32][68] = (float (*)[32][68])smraw;
  float* lsmem = (float*)(smraw + 34816);                   // [4][32]

  const int flat = blockIdx.x;               // 0..2047
  const int hk = flat & 7;                   // XCD-pinned (2048%8==0)
  const int b = (flat >> 3) & 1;
  const int h2 = (flat >> 4) & 3;
  const int qt = flat >> 6;                  // 0..31
  const int h = hk * 4 + h2;
  const int q0 = qt * 32;
  const int bh = b * 8 + hk;

  const int tid = threadIdx.x;
  const int lane = tid & 63, w = tid >> 6;
  const int l31 = lane & 31, hh = lane >> 5;

  union U8 { bf16x8 v; unsigned short u[8]; };
  union PB { unsigned int w4[4]; bf16x8 v; };

  const unsigned short* KT = Kc + (size_t)bh * 131072;
  const unsigned short* VT = Vc + (size_t)bh * 131072;
  unsigned short* vwave = vst + w * 4096;    // wave-private V stage (8 KB)

  // Q as persistent B-operand frags: lane holds Q[d][q=l31], frag ks covers
  // d = ks*16 + hh*8 + j; RoPE + scale*log2(e) folded in.
  const float SC = 0.125f * 1.44269504f;
  bf16x8 qB[4];
  {
    int row = q0 + l31;
    const unsigned short* qrow = qkv + (size_t)(b * 1024 + row) * 3072 + h * 64;
    U8 raw[4];
#pragma unroll
    for (int ks = 0; ks < 4; ++ks)
      raw[ks].v = *(const bf16x8*)(qrow + ks * 16 + hh * 8);
#pragma unroll
    for (int ks = 0; ks < 2; ++ks) {
      int dbase = ks * 16 + hh * 8;
      float4 ca = *(const float4*)(cosb + row * 64 + dbase);
      float4 cb = *(const float4*)(cosb + row * 64 + dbase + 4);
      float4 sa = *(const float4*)(sinb + row * 64 + dbase);
      float4 sb = *(const float4*)(sinb + row * 64 + dbase + 4);
      float c[8] = {ca.x, ca.y, ca.z, ca.w, cb.x, cb.y, cb.z, cb.w};
      float sn[8] = {sa.x, sa.y, sa.z, sa.w, sb.x, sb.y, sb.z, sb.w};
      U8 flo, fhi;
#pragma unroll
      for (int j = 0; j < 8; ++j) {
        float ql = bf2f(raw[ks].u[j]), qh = bf2f(raw[ks + 2].u[j]);
        float cc = c[j] * SC, ss = sn[j] * SC;
        flo.u[j] = f2bf(ql * cc - qh * ss);
        fhi.u[j] = f2bf(qh * cc + ql * ss);
      }
      qB[ks] = flo.v;
      qB[ks + 2] = fhi.v;
    }
  }

  // persistent zero accumulator seed (kills per-tile sacc re-zeroing)
  f32x16 ZV;
#pragma unroll
  for (int i = 0; i < 16; ++i) ZV[i] = 0.f;

  f32x16 oaccT[2];
  oaccT[0] = ZV; oaccT[1] = ZV;
  float lsum = 0.f;

  const int ntile = (q0 + 1119) >> 6;        // 17..32

  for (int kt = w; kt < ntile; kt += 4) {
    // compiler fence: keep this iteration's DMA after last iteration's V reads
    asm volatile("" ::: "memory");

    // K frags direct to registers FIRST (QK unblocks as early as possible)
    const unsigned short* kb = KT + (size_t)kt * 4096 + lane * 8;
    bf16x8 kf[8];
#pragma unroll
    for (int f = 0; f < 8; ++f) kf[f] = *(const bf16x8*)(kb + f * 512);

    // async V stage (no registers): frag f -> vwave[f*512 + lane*8];
    // covered by QK MFMAs + softmax below
    const unsigned short* vb = VT + (size_t)kt * 4096 + lane * 8;
#pragma unroll
    for (int f = 0; f < 8; ++f)
      gload_lds16(vb + f * 512, vwave + f * 512);

    // S^T = K @ (Q*SC'), first MFMA of each group seeds from ZV
    __builtin_amdgcn_s_setprio(1);
    f32x16 sacc[2];
    sacc[0] = __builtin_amdgcn_mfma_f32_32x32x16_bf16(kf[0], qB[0], ZV, 0, 0, 0);
#pragma unroll
    for (int ks = 1; ks < 4; ++ks)
      sacc[0] = __builtin_amdgcn_mfma_f32_32x32x16_bf16(kf[ks], qB[ks], sacc[0], 0, 0, 0);
    sacc[1] = __builtin_amdgcn_mfma_f32_32x32x16_bf16(kf[4], qB[0], ZV, 0, 0, 0);
#pragma unroll
    for (int ks = 1; ks < 4; ++ks)
      sacc[1] = __builtin_amdgcn_mfma_f32_32x32x16_bf16(kf[4 + ks], qB[ks], sacc[1], 0, 0, 0);
    __builtin_amdgcn_s_setprio(0);

    // in-register softmax-lite: lane owns q=q0+l31; t = t0+mf*32+(r&3)+8*(r>>2)+4*hh
    const int t0 = kt * 64;
    unsigned int pk[2][8];
    const bool diag = (t0 + 63 > q0 + Pc);
    if (!diag) {
#pragma unroll
      for (int mf = 0; mf < 2; ++mf)
#pragma unroll
        for (int p = 0; p < 8; ++p) {
          float e0 = exp2_fast(sacc[mf][2 * p]);
          float e1 = exp2_fast(sacc[mf][2 * p + 1]);
          lsum += e0 + e1;
          pk[mf][p] = cvtpk_bf16(e0, e1);
        }
    } else {
      int rg = q0 + l31 + Pc;
#pragma unroll
      for (int mf = 0; mf < 2; ++mf)
#pragma unroll
        for (int p = 0; p < 8; ++p) {
          int r0 = 2 * p;
          int tg = t0 + mf * 32 + (r0 & 3) + 8 * (r0 >> 2) + 4 * hh;
          float e0 = (tg <= rg) ? exp2_fast(sacc[mf][r0]) : 0.f;
          float e1 = (tg + 1 <= rg) ? exp2_fast(sacc[mf][r0 + 1]) : 0.f;
          lsum += e0 + e1;
          pk[mf][p] = cvtpk_bf16(e0, e1);
        }
    }

    // P^T -> PV B-frags (verified v7 mapping)
    PB pb[4];
#pragma unroll
    for (int ks = 0; ks < 4; ++ks) {
      int mf = ks >> 1, o = (ks & 1) * 4;
      unsigned int a0 = pk[mf][o + 0], b0 = pk[mf][o + 2];
      unsigned int a1 = pk[mf][o + 1], b1 = pk[mf][o + 3];
      plane32_swap(a0, b0);
      plane32_swap(a1, b1);
      pb[ks].w4[0] = a0; pb[ks].w4[1] = a1; pb[ks].w4[2] = b0; pb[ks].w4[3] = b1;
    }

    // V DMA has been in flight since tile top; drain and read frags from LDS
    asm volatile("s_waitcnt vmcnt(0)" ::: "memory");
    bf16x8 vf[8];
#pragma unroll
    for (int f = 0; f < 8; ++f)
      vf[f] = *(const bf16x8*)(vwave + f * 512 + lane * 8);

    // O^T += V^T @ P^T
    __builtin_amdgcn_s_setprio(1);
#pragma unroll
    for (int md = 0; md < 2; ++md)
#pragma unroll
      for (int ks = 0; ks < 4; ++ks)
        oaccT[md] = __builtin_amdgcn_mfma_f32_32x32x16_bf16(vf[md * 4 + ks], pb[ks].v, oaccT[md], 0, 0, 0);
    __builtin_amdgcn_s_setprio(0);
  }

  // ---- additive 4-wave combine (comb aliases vstage: barrier first) ----
  __syncthreads();
  lsum += __shfl_xor(lsum, 32);
  if (hh == 0) lsmem[w * 32 + l31] = lsum;
#pragma unroll
  for (int md = 0; md < 2; ++md)
#pragma unroll
    for (int g = 0; g < 4; ++g) {
      float4 fv = {oaccT[md][4 * g + 0], oaccT[md][4 * g + 1],
                   oaccT[md][4 * g + 2], oaccT[md][4 * g + 3]};
      *(float4*)&comb[w][l31][md * 32 + 8 * g + 4 * hh] = fv;
    }
  __syncthreads();

  const int q = tid >> 3, c8 = (tid & 7) * 8;
  float a8[8];
#pragma unroll
  for (int i = 0; i < 8; ++i) a8[i] = 0.f;
#pragma unroll
  for (int wv = 0; wv < 4; ++wv) {
    float4 p0 = *(const float4*)&comb[wv][q][c8];
    float4 p1 = *(const float4*)&comb[wv][q][c8 + 4];
    a8[0] += p0.x; a8[1] += p0.y; a8[2] += p0.z; a8[3] += p0.w;
    a8[4] += p1.x; a8[5] += p1.y; a8[6] += p1.z; a8[7] += p1.w;
  }
  float linv = 1.f / (lsmem[0 * 32 + q] + lsmem[1 * 32 + q] + lsmem[2 * 32 + q] + lsmem[3 * 32 + q]);
  uint4 ov;
  ov.x = cvtpk_bf16(a8[0] * linv, a8[1] * linv);
  ov.y = cvtpk_bf16(a8[2] * linv, a8[3] * linv);
  ov.z = cvtpk_bf16(a8[4] * linv, a8[5] * linv);
  ov.w = cvtpk_bf16(a8[6] * linv, a8[7] * linv);
  int row = b * 1024 + q0 + q;
  *(uint4*)(O + (size_t)row * 2048 + h * 64 + c8) = ov;
}

extern "C" void kernel_launch(void* const* d_in, const int* in_sizes, int n_in,
                              void* d_out, int out_size, void* d_ws, size_t ws_size,
                              hipStream_t stream) {
  const float* x      = (const float*)d_in[0];
  const float* cosb   = (const float*)d_in[2];
  const float* sinb   = (const float*)d_in[3];
  const float* past_k = (const float*)d_in[4];
  const float* past_v = (const float*)d_in[5];
  const float* Wq     = (const float*)d_in[6];
  const float* bq     = (const float*)d_in[7];
  const float* Wk     = (const float*)d_in[8];
  const float* bk     = (const float*)d_in[9];
  const float* Wv     = (const float*)d_in[10];
  const float* bv     = (const float*)d_in[11];
  const float* Wo     = (const float*)d_in[12];
  float* out = (float*)d_out;

  char* ws = (char*)d_ws;
  unsigned short* xb    = (unsigned short*)(ws + ((size_t)0 << 20));   // 8 MB
  unsigned short* WqkvT = (unsigned short*)(ws + ((size_t)8 << 20));   // 12 MB
  unsigned short* WoT   = (unsigned short*)(ws + ((size_t)20 << 20));  // 8 MB
  unsigned short* qkvb  = (unsigned short*)(ws + ((size_t)28 << 20));  // 12 MB
  unsigned short* Kc    = (unsigned short*)(ws + ((size_t)40 << 20));  // 4 MB
  unsigned short* Vc    = (unsigned short*)(ws + ((size_t)44 << 20));  // 4 MB
  unsigned short* attno = (unsigned short*)(ws + ((size_t)48 << 20));  // 8 MB

  cast_x_kernel<<<4096, 256, 0, stream>>>(x, xb);
  transpose_all_kernel<<<dim3(160, 64), dim3(32, 8), 0, stream>>>(Wq, Wk, Wv, Wo, WqkvT, WoT);

  gemm_kernel<64, false><<<dim3(24, 32), 256, 0, stream>>>(xb, WqkvT, bq, bk, bv, qkvb, 3072);

  build_kv_kernel<<<512, 256, 0, stream>>>(qkvb, past_k, past_v, cosb, sinb, Kc, Vc);

  attn_kernel<<<2048, 256, 0, stream>>>(qkvb, Kc, Vc, cosb, sinb, attno);

  gemm_kernel<64, true><<<dim3(16, 32), 256, 0, stream>>>(attno, WoT, nullptr, nullptr, nullptr, out, 2048);
}

// Round 10
// 258.598 us; speedup vs baseline: 1.0467x; 1.0251x over previous
//
#include <hip/hip_runtime.h>
#include <stdint.h>

#define Bc   2
#define Lc   1024
#define Pc   1024
#define Tc   2048
#define HIDc 2048
#define NHc  32
#define NKVc 8
#define Dc   64

typedef __bf16 bf16x8 __attribute__((ext_vector_type(8)));
typedef float f32x4 __attribute__((ext_vector_type(4)));
typedef float f32x16 __attribute__((ext_vector_type(16)));

__device__ inline unsigned short f2bf(float f) {
  union { float f; uint32_t u; } v; v.f = f;
  uint32_t u = v.u;
  uint32_t r = (u + 0x7fffu + ((u >> 16) & 1u)) >> 16;
  return (unsigned short)r;
}
__device__ inline float bf2f(unsigned short h) {
  union { uint32_t u; float f; } v; v.u = ((uint32_t)h) << 16;
  return v.f;
}
__device__ inline float exp2_fast(float x) {
#if defined(__has_builtin)
#if __has_builtin(__builtin_amdgcn_exp2f)
  return __builtin_amdgcn_exp2f(x);
#else
  return exp2f(x);
#endif
#else
  return exp2f(x);
#endif
}
// pack two f32 -> one u32 of 2x bf16 (low = a, high = b); no builtin on gfx950
__device__ inline unsigned int cvtpk_bf16(float a, float b) {
  unsigned int r;
  asm("v_cvt_pk_bf16_f32 %0, %1, %2" : "=v"(r) : "v"(a), "v"(b));
  return r;
}
// v_permlane32_swap_b32: a.hi32lanes <-> b.lo32lanes
__device__ inline void plane32_swap(unsigned int& a, unsigned int& b) {
  asm("v_permlane32_swap_b32 %0, %1" : "+v"(a), "+v"(b));
}

typedef const __attribute__((address_space(1))) unsigned int* gas1_t;
typedef __attribute__((address_space(3))) unsigned int* las3_t;
__device__ inline void gload_lds16(const void* g, void* l) {
  __builtin_amdgcn_global_load_lds((gas1_t)g, (las3_t)l, 16, 0, 0);
}

// ---------------- fused prep: cast x (fp32->bf16) + transpose 4 weights ----------------
// One launch instead of two (launch-gap cut; top-5 is all-attn so these were
// never the bottleneck, but each removed dispatch saves its gap).
__global__ void prep_kernel(const float* __restrict__ x, unsigned short* __restrict__ xb,
                            const float* __restrict__ Wq, const float* __restrict__ Wk,
                            const float* __restrict__ Wv, const float* __restrict__ Wo,
                            unsigned short* __restrict__ WqkvT,
                            unsigned short* __restrict__ WoT) {
  __shared__ float s[32][33];
  const int tid = threadIdx.x;
  if (blockIdx.x < 4096) {
    int i = (blockIdx.x * 256 + tid) * 4;
    float4 v = *(const float4*)(x + i);
    ushort4 o;
    o.x = f2bf(v.x); o.y = f2bf(v.y); o.z = f2bf(v.z); o.w = f2bf(v.w);
    *(ushort4*)(xb + i) = o;
    return;
  }
  int bx2 = blockIdx.x - 4096;       // 0..10239
  int bx = bx2 % 160;
  int k0 = (bx2 / 160) * 32;         // 0..2016
  const float* W;
  unsigned short* dst;
  int N, n0, drow;
  if (bx < 64)       { W = Wq; dst = WqkvT; N = 2048; n0 = bx * 32;        drow = n0; }
  else if (bx < 80)  { W = Wk; dst = WqkvT; N = 512;  n0 = (bx - 64) * 32; drow = 2048 + n0; }
  else if (bx < 96)  { W = Wv; dst = WqkvT; N = 512;  n0 = (bx - 80) * 32; drow = 2560 + n0; }
  else               { W = Wo; dst = WoT;   N = 2048; n0 = (bx - 96) * 32; drow = n0; }
  int tx = tid & 31, ty = tid >> 5;  // (32,8)
#pragma unroll
  for (int j = 0; j < 4; ++j)
    s[ty + j * 8][tx] = W[(size_t)(k0 + ty + j * 8) * N + n0 + tx];
  __syncthreads();
#pragma unroll
  for (int j = 0; j < 4; ++j)
    dst[(size_t)(drow + ty + j * 8) * 2048 + k0 + tx] = f2bf(s[tx][ty + j * 8]);
}

// ---------------- GEMM: TM x 128 tile, pipelined K-loop (R7 best-known config) ----------------
template <int TM, bool OUT_F32>
__global__ __launch_bounds__(256, 2) void gemm_kernel(
    const unsigned short* __restrict__ A, const unsigned short* __restrict__ BT,
    const float* __restrict__ bq, const float* __restrict__ bk, const float* __restrict__ bv,
    void* __restrict__ Cout, int N) {
  const int K = 2048;
  const int MI = TM / 32;       // m-frags per wave
  __shared__ unsigned short sA[2][TM * 32];
  __shared__ unsigned short sB[2][128 * 32];
  const int m0 = blockIdx.y * TM, n0 = blockIdx.x * 128;
  const int tid = threadIdx.x;
  const int lane = tid & 63, w = tid >> 6;
  const int l15 = lane & 15, quad = lane >> 4;
  const int wm = (w & 1) * (TM / 2), wn = (w >> 1) * 64;

  f32x4 acc[MI][4];
#pragma unroll
  for (int i = 0; i < MI; ++i)
#pragma unroll
    for (int j = 0; j < 4; ++j) {
      f32x4 z = {0.f, 0.f, 0.f, 0.f};
      acc[i][j] = z;
    }

  const unsigned short* ga = A + (size_t)(m0 + (tid >> 2)) * K + (tid & 3) * 8;
  const unsigned short* gb = BT + (size_t)(n0 + (tid >> 2)) * K + (tid & 3) * 8;

  auto issue = [&](int tile, int buf) {
    int kb = tile * 32;
#pragma unroll
    for (int i = 0; i < TM / 64; ++i)
      gload_lds16(ga + (size_t)(i * 64) * K + kb, &sA[buf][i * 64 * 32 + tid * 8]);
    gload_lds16(gb + kb, &sB[buf][tid * 8]);
    gload_lds16(gb + (size_t)64 * K + kb, &sB[buf][64 * 32 + tid * 8]);
  };

  issue(0, 0);
  for (int t = 0; t < 64; ++t) {
    int tn = (t + 1 < 64) ? t + 1 : 63;  // clamped dummy prefetch on last iter
    issue(tn, (t + 1) & 1);
    if (TM == 128)
      asm volatile("s_waitcnt vmcnt(4)" ::: "memory");
    else
      asm volatile("s_waitcnt vmcnt(3)" ::: "memory");
    __builtin_amdgcn_s_barrier();
    const unsigned short* bA = sA[t & 1];
    const unsigned short* bB = sB[t & 1];
    bf16x8 af[MI], bfr[4];
#pragma unroll
    for (int i = 0; i < MI; ++i)
      af[i] = *(const bf16x8*)(bA + (wm + i * 16 + l15) * 32 + quad * 8);
#pragma unroll
    for (int i = 0; i < 4; ++i)
      bfr[i] = *(const bf16x8*)(bB + (wn + i * 16 + l15) * 32 + quad * 8);
#pragma unroll
    for (int mi = 0; mi < MI; ++mi)
#pragma unroll
      for (int ni = 0; ni < 4; ++ni)
        acc[mi][ni] = __builtin_amdgcn_mfma_f32_16x16x32_bf16(af[mi], bfr[ni], acc[mi][ni], 0, 0, 0);
    asm volatile("s_waitcnt lgkmcnt(0)" ::: "memory");
    __builtin_amdgcn_s_barrier();
  }

#pragma unroll
  for (int mi = 0; mi < MI; ++mi)
#pragma unroll
    for (int ni = 0; ni < 4; ++ni) {
      int col = n0 + wn + ni * 16 + l15;
      float bvv = 0.f;
      if (bq) bvv = (col < 2048) ? bq[col] : (col < 2560 ? bk[col - 2048] : bv[col - 2560]);
#pragma unroll
      for (int r = 0; r < 4; ++r) {
        int row = m0 + wm + mi * 16 + quad * 4 + r;
        float v = acc[mi][ni][r] + bvv;
        if (OUT_F32)
          ((float*)Cout)[(size_t)row * N + col] = v;
        else
          ((unsigned short*)Cout)[(size_t)row * N + col] = f2bf(v);
      }
    }
}

// ------- fused KV-cache build, FRAGMENT-LINEAR output layout -------
// Kc/Vc layout: [bh][tile(32)][frag(8)][lane(64)][8 bf16]  (4 MB each).
// K frag f=mf*4+ks, lane l: K[t0+mf*32+(l&31)][ks*16+(l>>5)*8+j]
// V frag f=md*4+ks, lane l: V^T[md*32+(l&31)][t0+ks*16+(l>>5)*8+j]
__global__ void build_kv_kernel(const unsigned short* __restrict__ qkv,
                                const float* __restrict__ past_k,
                                const float* __restrict__ past_v,
                                const float* __restrict__ cosb, const float* __restrict__ sinb,
                                unsigned short* __restrict__ Kc,
                                unsigned short* __restrict__ Vc) {
  __shared__ __align__(16) unsigned short sK[64 * 72];   // [t-local][d], stride 72
  __shared__ __align__(16) unsigned short sVT[64 * 72];  // [d][t-local], stride 72
  union U8 { bf16x8 v; unsigned short u[8]; };

  const int bid = blockIdx.x;         // bh*32 + tt
  const int bh = bid >> 5, tt = bid & 31;
  const int b = bh >> 3, hk = bh & 7;
  const int tid = threadIdx.x;
  const int tl = tid >> 2;            // 0..63 row in tile
  const int c16 = (tid & 3) * 16;     // col start

  const int t = tt * 64 + tl;

  // ---- K row -> sK[t][d] ----
  U8 ko0, ko1;
  if (tt < 16) {
    const float* src = past_k + (((size_t)bh * 1024 + t) * 64 + c16);
#pragma unroll
    for (int i = 0; i < 8; ++i) ko0.u[i] = f2bf(src[i]);
#pragma unroll
    for (int i = 0; i < 8; ++i) ko1.u[i] = f2bf(src[8 + i]);
  } else {
    const int l = t - 1024;
    const unsigned short* krow = qkv + ((size_t)(b * 1024 + l)) * 3072 + 2048 + hk * 64;
    const int po = (c16 < 32) ? 32 : -32;
    const float sgn = (c16 < 32) ? -1.f : 1.f;
    U8 own0, own1, par0, par1;
    own0.v = *(const bf16x8*)(krow + c16);
    own1.v = *(const bf16x8*)(krow + c16 + 8);
    par0.v = *(const bf16x8*)(krow + c16 + po);
    par1.v = *(const bf16x8*)(krow + c16 + po + 8);
    const float* cb = cosb + l * 64 + c16;
    const float* sb = sinb + l * 64 + c16;
#pragma unroll
    for (int i = 0; i < 8; ++i)
      ko0.u[i] = f2bf(bf2f(own0.u[i]) * cb[i] + sgn * bf2f(par0.u[i]) * sb[i]);
#pragma unroll
    for (int i = 0; i < 8; ++i)
      ko1.u[i] = f2bf(bf2f(own1.u[i]) * cb[8 + i] + sgn * bf2f(par1.u[i]) * sb[8 + i]);
  }
  *(bf16x8*)&sK[tl * 72 + c16] = ko0.v;
  *(bf16x8*)&sK[tl * 72 + c16 + 8] = ko1.v;

  // ---- V row -> sVT[d][t] (transpose via scalar writes) ----
  if (tt < 16) {
    const float* src = past_v + (((size_t)bh * 1024 + t) * 64 + c16);
#pragma unroll
    for (int i = 0; i < 16; ++i) sVT[(c16 + i) * 72 + tl] = f2bf(src[i]);
  } else {
    const unsigned short* vrow = qkv + ((size_t)(b * 1024 + (t - 1024))) * 3072 + 2560 + hk * 64 + c16;
    U8 v0, v1;
    v0.v = *(const bf16x8*)(vrow);
    v1.v = *(const bf16x8*)(vrow + 8);
#pragma unroll
    for (int i = 0; i < 8; ++i) sVT[(c16 + i) * 72 + tl] = v0.u[i];
#pragma unroll
    for (int i = 0; i < 8; ++i) sVT[(c16 + 8 + i) * 72 + tl] = v1.u[i];
  }

  __syncthreads();

  // ---- write frag-linear chunks (coalesced 16B global stores) ----
  unsigned short* KD = Kc + (size_t)bh * 131072 + (size_t)tt * 4096;
  unsigned short* VD = Vc + (size_t)bh * 131072 + (size_t)tt * 4096;
#pragma unroll
  for (int half = 0; half < 2; ++half) {
    int c = tid + half * 256;
    int f = c >> 6, l = c & 63;
    int col = (f & 3) * 16 + (l >> 5) * 8;
    int row = (f >> 2) * 32 + (l & 31);
    *(bf16x8*)(KD + f * 512 + l * 8) = *(const bf16x8*)&sK[row * 72 + col];
    *(bf16x8*)(VD + f * 512 + l * 8) = *(const bf16x8*)&sVT[row * 72 + col];
  }
}

// ---------------- flash attention v13: exact v11 + LPT block ordering ----------------
// v12 post-mortem: setprio/zero-seed/reorder all neutral-to-negative (57.0 vs
// v11's 51.9/55.4) -- reverted wholesale. ONE new change vs v11: ntile varies
// 17..32 with qt, and qt = flat>>6 dispatched the HEAVIEST blocks (qt=31, 32
// tiles) LAST -> ~7-tile tail on the final residency wave. LPT fix: reverse
// the qt mapping so heavy blocks start first. Everything else identical to
// the R7 measured-best kernel (51.9us, VGPR 64, no spill).
__global__ __launch_bounds__(256, 4) void attn_kernel(
    const unsigned short* __restrict__ qkv,  // [B*L][3072]
    const unsigned short* __restrict__ Kc,   // frag-linear
    const unsigned short* __restrict__ Vc,   // frag-linear
    const float* __restrict__ cosb, const float* __restrict__ sinb,
    unsigned short* __restrict__ O) {        // [B*L][2048]
  // union: main loop uses vstage[4][4096] (32 KB); epilogue uses
  // comb[4][32][68] f32 (34816 B) + lsmem[4][32] (512 B) = 35328 B
  __shared__ __align__(16) char smraw[35328];
  unsigned short* vst = (unsigned short*)smraw;             // [4][4096]
  float (*comb)[32][68] = (float (*)[32][68])smraw;
  float* lsmem = (float*)(smraw + 34816);                   // [4][32]

  const int flat = blockIdx.x;               // 0..2047
  const int hk = flat & 7;                   // XCD-pinned (2048%8==0)
  const int b = (flat >> 3) & 1;
  const int h2 = (flat >> 4) & 3;
  const int qt = 31 - (flat >> 6);           // LPT: heavy (high-qt) blocks first
  const int h = hk * 4 + h2;
  const int q0 = qt * 32;
  const int bh = b * 8 + hk;

  const int tid = threadIdx.x;
  const int lane = tid & 63, w = tid >> 6;
  const int l31 = lane & 31, hh = lane >> 5;

  union U8 { bf16x8 v; unsigned short u[8]; };
  union PB { unsigned int w4[4]; bf16x8 v; };

  const unsigned short* KT = Kc + (size_t)bh * 131072;
  const unsigned short* VT = Vc + (size_t)bh * 131072;
  unsigned short* vwave = vst + w * 4096;    // wave-private V stage (8 KB)

  // Q as persistent B-operand frags: lane holds Q[d][q=l31], frag ks covers
  // d = ks*16 + hh*8 + j; RoPE + scale*log2(e) folded in.
  const float SC = 0.125f * 1.44269504f;
  bf16x8 qB[4];
  {
    int row = q0 + l31;
    const unsigned short* qrow = qkv + (size_t)(b * 1024 + row) * 3072 + h * 64;
    U8 raw[4];
#pragma unroll
    for (int ks = 0; ks < 4; ++ks)
      raw[ks].v = *(const bf16x8*)(qrow + ks * 16 + hh * 8);
#pragma unroll
    for (int ks = 0; ks < 2; ++ks) {
      int dbase = ks * 16 + hh * 8;
      float4 ca = *(const float4*)(cosb + row * 64 + dbase);
      float4 cb = *(const float4*)(cosb + row * 64 + dbase + 4);
      float4 sa = *(const float4*)(sinb + row * 64 + dbase);
      float4 sb = *(const float4*)(sinb + row * 64 + dbase + 4);
      float c[8] = {ca.x, ca.y, ca.z, ca.w, cb.x, cb.y, cb.z, cb.w};
      float sn[8] = {sa.x, sa.y, sa.z, sa.w, sb.x, sb.y, sb.z, sb.w};
      U8 flo, fhi;
#pragma unroll
      for (int j = 0; j < 8; ++j) {
        float ql = bf2f(raw[ks].u[j]), qh = bf2f(raw[ks + 2].u[j]);
        float cc = c[j] * SC, ss = sn[j] * SC;
        flo.u[j] = f2bf(ql * cc - qh * ss);
        fhi.u[j] = f2bf(qh * cc + ql * ss);
      }
      qB[ks] = flo.v;
      qB[ks + 2] = fhi.v;
    }
  }

  f32x16 oaccT[2];
  {
    f32x16 z;
#pragma unroll
    for (int i = 0; i < 16; ++i) z[i] = 0.f;
    oaccT[0] = z; oaccT[1] = z;
  }
  float lsum = 0.f;

  const int ntile = (q0 + 1119) >> 6;        // 17..32

  for (int kt = w; kt < ntile; kt += 4) {
    // compiler fence: keep this iteration's DMA after last iteration's V reads
    asm volatile("" ::: "memory");
    // async V stage (no registers): frag f -> vwave[f*512 + lane*8]
    const unsigned short* vb = VT + (size_t)kt * 4096 + lane * 8;
#pragma unroll
    for (int f = 0; f < 8; ++f)
      gload_lds16(vb + f * 512, vwave + f * 512);

    // K frags direct to registers (the one exposed latency per tile)
    const unsigned short* kb = KT + (size_t)kt * 4096 + lane * 8;
    bf16x8 kf[8];
#pragma unroll
    for (int f = 0; f < 8; ++f) kf[f] = *(const bf16x8*)(kb + f * 512);

    // S^T = K @ (Q*SC')
    f32x16 sacc[2];
    {
      f32x16 z;
#pragma unroll
      for (int i = 0; i < 16; ++i) z[i] = 0.f;
      sacc[0] = z; sacc[1] = z;
    }
#pragma unroll
    for (int ks = 0; ks < 4; ++ks)
      sacc[0] = __builtin_amdgcn_mfma_f32_32x32x16_bf16(kf[ks], qB[ks], sacc[0], 0, 0, 0);
#pragma unroll
    for (int ks = 0; ks < 4; ++ks)
      sacc[1] = __builtin_amdgcn_mfma_f32_32x32x16_bf16(kf[4 + ks], qB[ks], sacc[1], 0, 0, 0);

    // in-register softmax-lite: lane owns q=q0+l31; t = t0+mf*32+(r&3)+8*(r>>2)+4*hh
    const int t0 = kt * 64;
    unsigned int pk[2][8];
    const bool diag = (t0 + 63 > q0 + Pc);
    if (!diag) {
#pragma unroll
      for (int mf = 0; mf < 2; ++mf)
#pragma unroll
        for (int p = 0; p < 8; ++p) {
          float e0 = exp2_fast(sacc[mf][2 * p]);
          float e1 = exp2_fast(sacc[mf][2 * p + 1]);
          lsum += e0 + e1;
          pk[mf][p] = cvtpk_bf16(e0, e1);
        }
    } else {
      int rg = q0 + l31 + Pc;
#pragma unroll
      for (int mf = 0; mf < 2; ++mf)
#pragma unroll
        for (int p = 0; p < 8; ++p) {
          int r0 = 2 * p;
          int tg = t0 + mf * 32 + (r0 & 3) + 8 * (r0 >> 2) + 4 * hh;
          float e0 = (tg <= rg) ? exp2_fast(sacc[mf][r0]) : 0.f;
          float e1 = (tg + 1 <= rg) ? exp2_fast(sacc[mf][r0 + 1]) : 0.f;
          lsum += e0 + e1;
          pk[mf][p] = cvtpk_bf16(e0, e1);
        }
    }

    // P^T -> PV B-frags (verified v7 mapping)
    PB pb[4];
#pragma unroll
    for (int ks = 0; ks < 4; ++ks) {
      int mf = ks >> 1, o = (ks & 1) * 4;
      unsigned int a0 = pk[mf][o + 0], b0 = pk[mf][o + 2];
      unsigned int a1 = pk[mf][o + 1], b1 = pk[mf][o + 3];
      plane32_swap(a0, b0);
      plane32_swap(a1, b1);
      pb[ks].w4[0] = a0; pb[ks].w4[1] = a1; pb[ks].w4[2] = b0; pb[ks].w4[3] = b1;
    }

    // V DMA has been in flight since tile top; drain and read frags from LDS
    asm volatile("s_waitcnt vmcnt(0)" ::: "memory");
    bf16x8 vf[8];
#pragma unroll
    for (int f = 0; f < 8; ++f)
      vf[f] = *(const bf16x8*)(vwave + f * 512 + lane * 8);

    // O^T += V^T @ P^T
#pragma unroll
    for (int md = 0; md < 2; ++md)
#pragma unroll
      for (int ks = 0; ks < 4; ++ks)
        oaccT[md] = __builtin_amdgcn_mfma_f32_32x32x16_bf16(vf[md * 4 + ks], pb[ks].v, oaccT[md], 0, 0, 0);
  }

  // ---- additive 4-wave combine (comb aliases vstage: barrier first) ----
  __syncthreads();
  lsum += __shfl_xor(lsum, 32);
  if (hh == 0) lsmem[w * 32 + l31] = lsum;
#pragma unroll
  for (int md = 0; md < 2; ++md)
#pragma unroll
    for (int g = 0; g < 4; ++g) {
      float4 fv = {oaccT[md][4 * g + 0], oaccT[md][4 * g + 1],
                   oaccT[md][4 * g + 2], oaccT[md][4 * g + 3]};
      *(float4*)&comb[w][l31][md * 32 + 8 * g + 4 * hh] = fv;
    }
  __syncthreads();

  const int q = tid >> 3, c8 = (tid & 7) * 8;
  float a8[8];
#pragma unroll
  for (int i = 0; i < 8; ++i) a8[i] = 0.f;
#pragma unroll
  for (int wv = 0; wv < 4; ++wv) {
    float4 p0 = *(const float4*)&comb[wv][q][c8];
    float4 p1 = *(const float4*)&comb[wv][q][c8 + 4];
    a8[0] += p0.x; a8[1] += p0.y; a8[2] += p0.z; a8[3] += p0.w;
    a8[4] += p1.x; a8[5] += p1.y; a8[6] += p1.z; a8[7] += p1.w;
  }
  float linv = 1.f / (lsmem[0 * 32 + q] + lsmem[1 * 32 + q] + lsmem[2 * 32 + q] + lsmem[3 * 32 + q]);
  uint4 ov;
  ov.x = cvtpk_bf16(a8[0] * linv, a8[1] * linv);
  ov.y = cvtpk_bf16(a8[2] * linv, a8[3] * linv);
  ov.z = cvtpk_bf16(a8[4] * linv, a8[5] * linv);
  ov.w = cvtpk_bf16(a8[6] * linv, a8[7] * linv);
  int row = b * 1024 + q0 + q;
  *(uint4*)(O + (size_t)row * 2048 + h * 64 + c8) = ov;
}

extern "C" void kernel_launch(void* const* d_in, const int* in_sizes, int n_in,
                              void* d_out, int out_size, void* d_ws, size_t ws_size,
                              hipStream_t stream) {
  const float* x      = (const float*)d_in[0];
  const float* cosb   = (const float*)d_in[2];
  const float* sinb   = (const float*)d_in[3];
  const float* past_k = (const float*)d_in[4];
  const float* past_v = (const float*)d_in[5];
  const float* Wq     = (const float*)d_in[6];
  const float* bq     = (const float*)d_in[7];
  const float* Wk     = (const float*)d_in[8];
  const float* bk     = (const float*)d_in[9];
  const float* Wv     = (const float*)d_in[10];
  const float* bv     = (const float*)d_in[11];
  const float* Wo     = (const float*)d_in[12];
  float* out = (float*)d_out;

  char* ws = (char*)d_ws;
  unsigned short* xb    = (unsigned short*)(ws + ((size_t)0 << 20));   // 8 MB
  unsigned short* WqkvT = (unsigned short*)(ws + ((size_t)8 << 20));   // 12 MB
  unsigned short* WoT   = (unsigned short*)(ws + ((size_t)20 << 20));  // 8 MB
  unsigned short* qkvb  = (unsigned short*)(ws + ((size_t)28 << 20));  // 12 MB
  unsigned short* Kc    = (unsigned short*)(ws + ((size_t)40 << 20));  // 4 MB
  unsigned short* Vc    = (unsigned short*)(ws + ((size_t)44 << 20));  // 4 MB
  unsigned short* attno = (unsigned short*)(ws + ((size_t)48 << 20));  // 8 MB

  prep_kernel<<<14336, 256, 0, stream>>>(x, xb, Wq, Wk, Wv, Wo, WqkvT, WoT);

  gemm_kernel<64, false><<<dim3(24, 32), 256, 0, stream>>>(xb, WqkvT, bq, bk, bv, qkvb, 3072);

  build_kv_kernel<<<512, 256, 0, stream>>>(qkvb, past_k, past_v, cosb, sinb, Kc, Vc);

  attn_kernel<<<2048, 256, 0, stream>>>(qkvb, Kc, Vc, cosb, sinb, attno);

  gemm_kernel<64, true><<<dim3(16, 32), 256, 0, stream>>>(attno, WoT, nullptr, nullptr, nullptr, out, 2048);
}